// Round 6
// baseline (133.868 us; speedup 1.0000x reference)
//
#include <hip/hip_runtime.h>
#include <hip/hip_bf16.h>
#include <math.h>

// Problem constants
#define BDIM    128   // batch graphs
#define N_NODES 512
#define KNB     10
#define FDIM    128
#define CDIM    40

// ---------------------------------------------------------------------------
// ALGEBRA (verified on-HW R2-R5, absmax 0.0): both SAGE layers are affine and
// only h[:,0,:] is consumed. With A_l/B_l = mp/self halves of w_sage[l]:
//   v1[b] = sum_{k,j} x[b, neigh[b, nb_k, j]]   (nb_k = neigh[b,0,k])
//   v2[b] = sum_k x[b, nb_k]
//   v4[b] = x[b,0]
//   p = A1·(0.01v1) + B1·(0.1v2) + b0
//   q = A1·(0.1v2)  + B1·v4      + b0
//   r = A2·p + B2·q + b1
//   z = L1·r + lin1_b
// then BatchNorm(batch)+ReLU+lin2+softmax.
//
// R6: latency-chain surgery. The harness re-poisons 268 MB of ws every
// iteration (evicts L2/L3), so ALL inputs are cold each replay. Changes:
//  - all stage-2/3/4 weights prefetched into REGISTERS at kernel top
//    (overlaps the dependent nb0->l2->gather miss chain),
//  - index resolution wave-local (shfl/readlane) -> 2 fewer barrier rounds,
//  - head logits: zs row in VGPRs + wave-uniform w2 (scalar loads).
// ---------------------------------------------------------------------------

__global__ __launch_bounds__(256, 1) void fused_z(
    const float* __restrict__ x,       // (128,512,128)
    const int*   __restrict__ neigh,   // (128,512,10)
    const float* __restrict__ w_sage,  // (2,128,256)
    const float* __restrict__ b_sage,  // (2,128)
    const float* __restrict__ lin1_w,  // (64,128)
    const float* __restrict__ lin1_b,  // (64)
    float*       __restrict__ z)       // (128,64)
{
    __shared__ __align__(16) float gpart[4][2][64];
    __shared__ __align__(16) float vpart[2][2][64];
    __shared__ __align__(16) float vs0[128], vs1[128], vs2[128];
    __shared__ __align__(16) float ppart[2][128], qpart[2][128];
    __shared__ __align__(16) float pv[128], qv[128], rv[128];
    __shared__ __align__(16) float rpart[2][128];
    __shared__ __align__(16) float zpart[4][64];
    __shared__ float bls[256];    // b_sage staged
    __shared__ float lbls[64];    // lin1_b staged

    const int b    = blockIdx.x;
    const int tid  = threadIdx.x;
    const int wv   = tid >> 6;         // wave 0..3
    const int lane = tid & 63;
    const int g    = tid & 127;        // row index for stages 2/3
    const int half = tid >> 7;         // 0/1
    const int* nbB = neigh + b * (N_NODES * KNB);
    const float* xb = x + (size_t)b * (N_NODES * FDIM);

    // ================= issue ALL independent loads first =================
    // 1-hop neighbor ids (same 40B line for all 4 waves -> MSHR-merged)
    int nbv = nbB[lane < 10 ? lane : 9];

    // stage-2 weights: row g of layer-0, A-seg + B-seg (32 float4)
    float4 wA[16], wB[16];
    {
        const float4* w4 = (const float4*)(w_sage + g * 256);
        #pragma unroll
        for (int i = 0; i < 16; ++i) wA[i] = w4[half * 16 + i];
        #pragma unroll
        for (int i = 0; i < 16; ++i) wB[i] = w4[32 + half * 16 + i];
    }
    // stage-3 weights: row g of layer-1, half selects A2/B2 (32 float4)
    float4 w3[32];
    {
        const float4* w43 = (const float4*)(w_sage + 32768 + g * 256 + half * 128);
        #pragma unroll
        for (int i = 0; i < 32; ++i) w3[i] = w43[i];
    }
    // stage-4 weights: lin1_w row j, quarter qt (8 float4)
    float4 w4r[8];
    {
        const float4* w44 = (const float4*)(lin1_w + (tid & 63) * 128 + (tid >> 6) * 32);
        #pragma unroll
        for (int i = 0; i < 8; ++i) w4r[i] = w44[i];
    }
    // biases
    float bsv = b_sage[tid];            // 256 elems exactly
    float lbv = lin1_b[tid & 63];
    // v4 = x[b,0,:] by wave 3 (independent)
    float v4lo = 0.f, v4hi = 0.f;
    if (wv == 3) { v4lo = xb[lane]; v4hi = xb[64 + lane]; }

    // ================= wave-local 2-hop index resolution =================
    int t  = wv * 25 + (lane < 25 ? lane : 24);
    int kk = t / 10;
    int jj = t - kk * 10;
    int l2row = __shfl(nbv, kk);                 // neigh[b,0,kk]
    int l2v   = nbB[l2row * KNB + jj];           // neigh[b, nb_kk, jj]

    // ================= gather: v1 (25 rows/wave), v2 (waves 0,1) ==========
    float a0 = 0.f, a1 = 0.f, a2 = 0.f, a3 = 0.f;
    #pragma unroll
    for (int i = 0; i < 25; i += 2) {
        int r0 = __builtin_amdgcn_readlane(l2v, i);
        const float* xr0 = xb + r0 * FDIM;
        a0 += xr0[lane]; a1 += xr0[64 + lane];
        if (i + 1 < 25) {
            int r1 = __builtin_amdgcn_readlane(l2v, i + 1);
            const float* xr1 = xb + r1 * FDIM;
            a2 += xr1[lane]; a3 += xr1[64 + lane];
        }
    }
    float c0 = 0.f, c1 = 0.f;
    if (wv < 2) {
        #pragma unroll
        for (int i = 0; i < 5; ++i) {
            int r = __builtin_amdgcn_readlane(nbv, wv * 5 + i);
            const float* xr = xb + r * FDIM;
            c0 += xr[lane]; c1 += xr[64 + lane];
        }
    }

    // stage partials + staged constants to LDS
    gpart[wv][0][lane] = a0 + a2;
    gpart[wv][1][lane] = a1 + a3;
    if (wv < 2) { vpart[wv][0][lane] = c0; vpart[wv][1][lane] = c1; }
    if (wv == 3) { vs2[lane] = v4lo; vs2[64 + lane] = v4hi; }
    bls[tid] = bsv;
    if (tid < 64) lbls[tid] = lbv;
    __syncthreads();                                        // barrier 1

    if (tid < 128) {
        int hf = tid >> 6, ln = tid & 63;
        vs0[tid] = (gpart[0][hf][ln] + gpart[1][hf][ln]
                  + gpart[2][hf][ln] + gpart[3][hf][ln]) * 0.01f;
        vs1[tid] = (vpart[0][hf][ln] + vpart[1][hf][ln]) * 0.1f;
    }
    __syncthreads();                                        // barrier 2

    // ================= stage 2: p,q (weights in regs) =====================
    {
        const float4* v0q = (const float4*)vs0;
        const float4* v1q = (const float4*)vs1;
        const float4* v2q = (const float4*)vs2;
        float p0 = 0.f, p1 = 0.f, q0 = 0.f, q1 = 0.f;
        #pragma unroll
        for (int i = 0; i < 16; ++i) {
            int f4 = half * 16 + i;
            float4 w = wA[i], va = v0q[f4], vb = v1q[f4];
            p0 = fmaf(w.x, va.x, p0); p1 = fmaf(w.y, va.y, p1);
            p0 = fmaf(w.z, va.z, p0); p1 = fmaf(w.w, va.w, p1);
            q0 = fmaf(w.x, vb.x, q0); q1 = fmaf(w.y, vb.y, q1);
            q0 = fmaf(w.z, vb.z, q0); q1 = fmaf(w.w, vb.w, q1);
        }
        #pragma unroll
        for (int i = 0; i < 16; ++i) {
            int f4 = half * 16 + i;
            float4 w = wB[i], va = v1q[f4], vb = v2q[f4];
            p0 = fmaf(w.x, va.x, p0); p1 = fmaf(w.y, va.y, p1);
            p0 = fmaf(w.z, va.z, p0); p1 = fmaf(w.w, va.w, p1);
            q0 = fmaf(w.x, vb.x, q0); q1 = fmaf(w.y, vb.y, q1);
            q0 = fmaf(w.z, vb.z, q0); q1 = fmaf(w.w, vb.w, q1);
        }
        ppart[half][g] = p0 + p1;
        qpart[half][g] = q0 + q1;
    }
    __syncthreads();                                        // barrier 3
    if (tid < 128) {
        pv[tid] = ppart[0][tid] + ppart[1][tid] + bls[tid];
        qv[tid] = qpart[0][tid] + qpart[1][tid] + bls[tid];
    }
    __syncthreads();                                        // barrier 4

    // ================= stage 3: r = A2*p + B2*q + b1 ======================
    {
        const float4* vvq = (const float4*)(half ? qv : pv);
        float a = 0.f, a2_ = 0.f;
        #pragma unroll
        for (int i = 0; i < 32; ++i) {
            float4 w = w3[i], v = vvq[i];
            a  = fmaf(w.x, v.x, a);  a2_ = fmaf(w.y, v.y, a2_);
            a  = fmaf(w.z, v.z, a);  a2_ = fmaf(w.w, v.w, a2_);
        }
        rpart[half][g] = a + a2_;
    }
    __syncthreads();                                        // barrier 5
    if (tid < 128) rv[tid] = rpart[0][tid] + rpart[1][tid] + bls[128 + tid];
    __syncthreads();                                        // barrier 6

    // ================= stage 4: z = L1*r + lin1_b =========================
    {
        const int j = tid & 63, qt = tid >> 6;
        const float4* rq = (const float4*)rv + qt * 8;
        float a = 0.f, a2_ = 0.f;
        #pragma unroll
        for (int i = 0; i < 8; ++i) {
            float4 w = w4r[i], v = rq[i];
            a  = fmaf(w.x, v.x, a);  a2_ = fmaf(w.y, v.y, a2_);
            a  = fmaf(w.z, v.z, a);  a2_ = fmaf(w.w, v.w, a2_);
        }
        zpart[qt][j] = a + a2_;
    }
    __syncthreads();                                        // barrier 7
    if (tid < 64)
        z[b * 64 + tid] = lbls[tid] + zpart[0][tid] + zpart[1][tid]
                        + zpart[2][tid] + zpart[3][tid];
}

// ---------------------------------------------------------------------------
// BatchNorm (over batch) + ReLU + lin2 + softmax. Single block, 256 threads.
// Logits: zs row cached in VGPRs, w2 indices wave-uniform -> scalar loads.
// ---------------------------------------------------------------------------
__global__ __launch_bounds__(256) void head_kernel(
    const float* __restrict__ z,      // (128, 64)
    const float* __restrict__ gamma,  // (64)
    const float* __restrict__ beta,   // (64)
    const float* __restrict__ w2,     // (40, 64)
    const float* __restrict__ b2,     // (40)
    float*       __restrict__ out)    // (128, 40)
{
    __shared__ float zs[128][65];     // +1 pad: column reads conflict-free
    __shared__ float sc[64], sh[64];
    __shared__ float lg[128][CDIM];
    const int tid = threadIdx.x;

    // ---- load z (coalesced global float4 -> scalar LDS, padded rows) ----
    {
        const float4* z4 = (const float4*)z;
        #pragma unroll
        for (int i = 0; i < 8; ++i) {
            int m = i * 256 + tid;          // float4 index 0..2047
            float4 v = z4[m];
            int row = m >> 4, col = (m & 15) * 4;
            zs[row][col + 0] = v.x; zs[row][col + 1] = v.y;
            zs[row][col + 2] = v.z; zs[row][col + 3] = v.w;
        }
    }
    __syncthreads();

    // ---- batch stats per feature ----
    if (tid < 64) {
        float s0 = 0.f, s1 = 0.f, q0 = 0.f, q1 = 0.f;
        for (int i = 0; i < 128; i += 2) {
            float a = zs[i][tid], c = zs[i + 1][tid];
            s0 += a; s1 += c;
            q0 = fmaf(a, a, q0); q1 = fmaf(c, c, q1);
        }
        float mu  = (s0 + s1) * (1.f / 128.f);
        float var = (q0 + q1) * (1.f / 128.f) - mu * mu;
        float rs  = rsqrtf(var + 1e-5f) * gamma[tid];
        sc[tid] = rs;
        sh[tid] = beta[tid] - mu * rs;
    }
    __syncthreads();

    // ---- normalize + relu in place ----
    #pragma unroll
    for (int i = 0; i < 8; ++i) {
        int m = i * 256 + tid;
        int row = m >> 4, col = (m & 15) * 4;
        #pragma unroll
        for (int k = 0; k < 4; ++k) {
            int j = col + k;
            zs[row][j] = fmaxf(fmaf(zs[row][j], sc[j], sh[j]), 0.f);
        }
    }
    __syncthreads();

    // ---- logits: thread (i = tid&127, half = tid>>7) -> 20 classes ----
    {
        const int i = tid & 127, hf = tid >> 7;
        const int cbase = hf * 20;
        float row[64];
        #pragma unroll
        for (int f = 0; f < 64; ++f) row[f] = zs[i][f];   // conflict-free (pad 65)
        for (int c = 0; c < 20; ++c) {
            const float* wr = w2 + (cbase + c) * 64;      // uniform -> s_load
            float t0 = 0.f, t1 = 0.f, t2 = 0.f, t3 = 0.f;
            #pragma unroll
            for (int f = 0; f < 64; f += 4) {
                t0 = fmaf(row[f + 0], wr[f + 0], t0);
                t1 = fmaf(row[f + 1], wr[f + 1], t1);
                t2 = fmaf(row[f + 2], wr[f + 2], t2);
                t3 = fmaf(row[f + 3], wr[f + 3], t3);
            }
            lg[i][cbase + c] = b2[cbase + c] + (t0 + t1) + (t2 + t3);
        }
    }
    __syncthreads();

    // ---- softmax per row ----
    if (tid < 128) {
        const int i = tid;
        float v[CDIM];
        float mx = -1e30f;
        #pragma unroll
        for (int c = 0; c < CDIM; ++c) { v[c] = lg[i][c]; mx = fmaxf(mx, v[c]); }
        float den = 0.f;
        #pragma unroll
        for (int c = 0; c < CDIM; ++c) { v[c] = __expf(v[c] - mx); den += v[c]; }
        float inv = 1.f / den;
        #pragma unroll
        for (int c = 0; c < CDIM; ++c) out[i * CDIM + c] = v[c] * inv;
    }
}

// ---------------------------------------------------------------------------
extern "C" void kernel_launch(void* const* d_in, const int* in_sizes, int n_in,
                              void* d_out, int out_size, void* d_ws, size_t ws_size,
                              hipStream_t stream)
{
    const float* x      = (const float*)d_in[0];
    const int*   neigh  = (const int*)  d_in[1];
    const float* w_sage = (const float*)d_in[2];
    const float* b_sage = (const float*)d_in[3];
    const float* lin1_w = (const float*)d_in[4];
    const float* lin1_b = (const float*)d_in[5];
    const float* bn_g   = (const float*)d_in[6];
    const float* bn_b   = (const float*)d_in[7];
    const float* lin2_w = (const float*)d_in[8];
    const float* lin2_b = (const float*)d_in[9];
    float* out = (float*)d_out;

    float* z = (float*)d_ws;   // 128*64 floats

    fused_z    <<<BDIM, 256, 0, stream>>>(x, neigh, w_sage, b_sage,
                                          lin1_w, lin1_b, z);
    head_kernel<<<1, 256, 0, stream>>>(z, bn_g, bn_b, lin2_w, lin2_b, out);
}

// Round 7
// 129.889 us; speedup vs baseline: 1.0306x; 1.0306x over previous
//
#include <hip/hip_runtime.h>
#include <hip/hip_bf16.h>
#include <math.h>

// Problem constants
#define BDIM    128   // batch graphs
#define N_NODES 512
#define KNB     10
#define FDIM    128
#define CDIM    40

// ---------------------------------------------------------------------------
// ALGEBRA (verified on-HW R2-R6, absmax 0.0): both SAGE layers are affine and
// only h[:,0,:] is consumed. With A_l/B_l = mp/self halves of w_sage[l]:
//   v1[b] = sum_{k,j} x[b, neigh[b, nb_k, j]]   (nb_k = neigh[b,0,k])
//   v2[b] = sum_k x[b, nb_k]
//   v4[b] = x[b,0]
//   p = A1·(0.01v1) + B1·(0.1v2) + b0
//   q = A1·(0.1v2)  + B1·v4      + b0
//   r = A2·p + B2·q + b1
//   z = L1·r + lin1_b
// then BatchNorm(batch)+ReLU+lin2+softmax.
//
// R7: the gather was the wall (R4-R6: VALUBusy <1%, 75 GB/s effective --
// scattered cold-miss/TLB chains into a cache that the harness's 268 MB
// poison evicts every replay). Invert it: v1/v2 are multiplicity-weighted
// sums, so STREAM each graph's whole 256 KB x-slice with coalesced
// independent float4 loads (bandwidth-bound, ~5.3 us for all of x at
// 6.3 TB/s) while the 2-hop indices resolve concurrently into an LDS
// multiplicity table. 2 blocks/graph -> 256 blocks saturate the chip.
// ---------------------------------------------------------------------------

__global__ __launch_bounds__(256, 1) void stream_agg(
    const float* __restrict__ x,       // (128,512,128)
    const int*   __restrict__ neigh,   // (128,512,10)
    float*       __restrict__ v1part,  // (128,2,128)
    float*       __restrict__ v2part)  // (128,2,128)
{
    __shared__ int   mm[N_NODES];      // m1 | (m2<<16)
    __shared__ int   nb0s[16];
    __shared__ float part1[8][128];
    __shared__ float part2[8][128];

    const int bb   = blockIdx.x;       // 0..255
    const int b    = bb >> 1;
    const int half = bb & 1;
    const int tid  = threadIdx.x;
    const int rg   = tid >> 5;         // row-group 0..7
    const int f4   = tid & 31;         // float4 column 0..31
    const float4* xb4 = (const float4*)(x + (size_t)b * (N_NODES * FDIM));
    const int*    nbB = neigh + b * (N_NODES * KNB);

    // ---- issue the block's entire 128 KB x-slice: 32 independent float4
    //      loads per thread, perfectly coalesced (lanes cover 2 full rows) ----
    float4 xa[32];
    #pragma unroll
    for (int i = 0; i < 32; ++i)
        xa[i] = xb4[(half * 256 + rg + 8 * i) * 32 + f4];

    // ---- concurrently: multiplicity table (overlaps the stream above) ----
    mm[tid]       = 0;
    mm[256 + tid] = 0;
    if (tid < 10) nb0s[tid] = nbB[tid];               // neigh[b,0,:]
    __syncthreads();
    if (tid < 100) {
        int k = tid / 10, jj = tid - k * 10;
        int l2 = nbB[nb0s[k] * KNB + jj];             // neigh[b, nb_k, jj]
        atomicAdd(&mm[l2], 1);                        // m1
    }
    if (tid < 10) atomicAdd(&mm[nb0s[tid]], 1 << 16); // m2
    __syncthreads();

    // ---- weighted accumulate over this block's 256 rows ----
    float4 a1 = make_float4(0.f, 0.f, 0.f, 0.f);
    float4 a2 = a1;
    #pragma unroll
    for (int i = 0; i < 32; ++i) {
        int n = half * 256 + rg + 8 * i;
        int m = mm[n];                                // LDS broadcast
        float m1 = (float)(m & 0xffff);
        float m2 = (float)(m >> 16);
        float4 v = xa[i];
        a1.x = fmaf(m1, v.x, a1.x); a1.y = fmaf(m1, v.y, a1.y);
        a1.z = fmaf(m1, v.z, a1.z); a1.w = fmaf(m1, v.w, a1.w);
        a2.x = fmaf(m2, v.x, a2.x); a2.y = fmaf(m2, v.y, a2.y);
        a2.z = fmaf(m2, v.z, a2.z); a2.w = fmaf(m2, v.w, a2.w);
    }
    *(float4*)&part1[rg][f4 * 4] = a1;
    *(float4*)&part2[rg][f4 * 4] = a2;
    __syncthreads();

    // ---- reduce 8 row-groups, write partials ----
    if (tid < 128) {
        float s = 0.f;
        #pragma unroll
        for (int r = 0; r < 8; ++r) s += part1[r][tid];
        v1part[(b * 2 + half) * 128 + tid] = s;
    } else {
        int f = tid - 128;
        float s = 0.f;
        #pragma unroll
        for (int r = 0; r < 8; ++r) s += part2[r][f];
        v2part[(b * 2 + half) * 128 + f] = s;
    }
}

// ---------------------------------------------------------------------------
// Combine partials + MLP stages (R3's proven structure). 128 blocks x 256.
// ---------------------------------------------------------------------------
__global__ __launch_bounds__(256) void mlp_z(
    const float* __restrict__ x,       // (128,512,128)
    const float* __restrict__ v1part,  // (128,2,128)
    const float* __restrict__ v2part,  // (128,2,128)
    const float* __restrict__ w_sage,  // (2,128,256)
    const float* __restrict__ b_sage,  // (2,128)
    const float* __restrict__ lin1_w,  // (64,128)
    const float* __restrict__ lin1_b,  // (64)
    float*       __restrict__ z)       // (128,64)
{
    __shared__ float part[2][2][128];
    __shared__ float vs0[128], vs1[128], vs2[128];
    __shared__ float pv[128], qv[128], rv[128];
    __shared__ float zpart[4][64];

    const int b   = blockIdx.x;
    const int tid = threadIdx.x;
    const int f   = tid & 127;
    const int h   = tid >> 7;
    const float* xb  = x + (size_t)b * (N_NODES * FDIM);
    const float* v1b = v1part + b * 256;
    const float* v2b = v2part + b * 256;

    // independent loads first
    if (h == 0) {
        vs0[f] = (v1b[f] + v1b[128 + f]) * 0.01f;
        vs1[f] = (v2b[f] + v2b[128 + f]) * 0.1f;
        vs2[f] = xb[f];                               // v4 = x[b,0,:]
    }
    __syncthreads();

    // ---- stage 2: p = A1*vs0 + B1*vs1, q = A1*vs1 + B1*vs2 ----
    {
        const float4* w4 = (const float4*)(w_sage + f * 256);
        float p0 = 0.f, p1 = 0.f, q0 = 0.f, q1 = 0.f;
        #pragma unroll
        for (int i = 0; i < 16; ++i) {
            int f4 = h * 16 + i;              // A1 segment
            float4 w = w4[f4];
            int fb = f4 * 4;
            p0 = fmaf(w.x, vs0[fb + 0], p0); p1 = fmaf(w.y, vs0[fb + 1], p1);
            p0 = fmaf(w.z, vs0[fb + 2], p0); p1 = fmaf(w.w, vs0[fb + 3], p1);
            q0 = fmaf(w.x, vs1[fb + 0], q0); q1 = fmaf(w.y, vs1[fb + 1], q1);
            q0 = fmaf(w.z, vs1[fb + 2], q0); q1 = fmaf(w.w, vs1[fb + 3], q1);
        }
        #pragma unroll
        for (int i = 0; i < 16; ++i) {
            int f4 = 32 + h * 16 + i;         // B1 segment
            float4 w = w4[f4];
            int fb = (f4 - 32) * 4;
            p0 = fmaf(w.x, vs1[fb + 0], p0); p1 = fmaf(w.y, vs1[fb + 1], p1);
            p0 = fmaf(w.z, vs1[fb + 2], p0); p1 = fmaf(w.w, vs1[fb + 3], p1);
            q0 = fmaf(w.x, vs2[fb + 0], q0); q1 = fmaf(w.y, vs2[fb + 1], q1);
            q0 = fmaf(w.z, vs2[fb + 2], q0); q1 = fmaf(w.w, vs2[fb + 3], q1);
        }
        part[0][h][f] = p0 + p1;
        part[1][h][f] = q0 + q1;
    }
    __syncthreads();
    if (h == 0) {
        float b0 = b_sage[f];
        pv[f] = part[0][0][f] + part[0][1][f] + b0;
        qv[f] = part[1][0][f] + part[1][1][f] + b0;
    }
    __syncthreads();

    // ---- stage 3: r = A2*p + B2*q + b1 ----
    {
        const float4* w4 = (const float4*)(w_sage + 32768 + f * 256 + h * 128);
        const float* vv = h ? qv : pv;
        float a0 = 0.f, a1 = 0.f;
        #pragma unroll
        for (int i = 0; i < 32; ++i) {
            float4 w = w4[i];
            int gb = i * 4;
            a0 = fmaf(w.x, vv[gb + 0], a0); a1 = fmaf(w.y, vv[gb + 1], a1);
            a0 = fmaf(w.z, vv[gb + 2], a0); a1 = fmaf(w.w, vv[gb + 3], a1);
        }
        part[0][h][f] = a0 + a1;
    }
    __syncthreads();
    if (h == 0) rv[f] = b_sage[128 + f] + part[0][0][f] + part[0][1][f];
    __syncthreads();

    // ---- stage 4: z = L1*r + lin1_b ----
    {
        const int j = tid & 63, qt = tid >> 6;
        const float4* w4 = (const float4*)(lin1_w + j * 128 + qt * 32);
        float a0 = 0.f, a1 = 0.f;
        #pragma unroll
        for (int i = 0; i < 8; ++i) {
            float4 w = w4[i];
            int gb = qt * 32 + i * 4;
            a0 = fmaf(w.x, rv[gb + 0], a0); a1 = fmaf(w.y, rv[gb + 1], a1);
            a0 = fmaf(w.z, rv[gb + 2], a0); a1 = fmaf(w.w, rv[gb + 3], a1);
        }
        zpart[qt][j] = a0 + a1;
    }
    __syncthreads();
    if (tid < 64)
        z[b * 64 + tid] = lin1_b[tid] + zpart[0][tid] + zpart[1][tid]
                        + zpart[2][tid] + zpart[3][tid];
}

// ---------------------------------------------------------------------------
// BatchNorm (over batch) + ReLU + lin2 + softmax. Single block. (verified R1)
// ---------------------------------------------------------------------------
__global__ __launch_bounds__(128) void head_kernel(
    const float* __restrict__ z,      // (128, 64)
    const float* __restrict__ gamma,  // (64)
    const float* __restrict__ beta,   // (64)
    const float* __restrict__ w2,     // (40, 64)
    const float* __restrict__ b2,     // (40)
    float*       __restrict__ out)    // (128, 40)
{
    __shared__ float zs[128][65];
    __shared__ float sc[64], sh[64];
    const int tid = threadIdx.x;

    for (int i = 0; i < 64; ++i) {
        int idx = i * 128 + tid;
        zs[idx >> 6][idx & 63] = z[idx];
    }
    __syncthreads();

    if (tid < 64) {
        float s = 0.f, ss = 0.f;
        for (int i = 0; i < 128; ++i) {
            float v = zs[i][tid];
            s += v; ss += v * v;
        }
        float mu  = s * (1.f / 128.f);
        float var = ss * (1.f / 128.f) - mu * mu;
        float rs  = rsqrtf(var + 1e-5f) * gamma[tid];
        sc[tid] = rs;
        sh[tid] = beta[tid] - mu * rs;
    }
    __syncthreads();

    {
        int j = tid & 63;
        for (int i = tid >> 6; i < 128; i += 2) {
            float v = fmaf(zs[i][j], sc[j], sh[j]);
            zs[i][j] = fmaxf(v, 0.f);
        }
    }
    __syncthreads();

    {
        int i = tid;
        float lg[CDIM];
        float mx = -1e30f;
        #pragma unroll 4
        for (int c = 0; c < CDIM; ++c) {
            const float* w = w2 + c * 64;
            float s = b2[c];
            for (int ff = 0; ff < 64; ++ff) s = fmaf(zs[i][ff], w[ff], s);
            lg[c] = s;
            mx = fmaxf(mx, s);
        }
        float den = 0.f;
        for (int c = 0; c < CDIM; ++c) {
            lg[c] = __expf(lg[c] - mx);
            den += lg[c];
        }
        float inv = 1.f / den;
        for (int c = 0; c < CDIM; ++c) out[i * CDIM + c] = lg[c] * inv;
    }
}

// ---------------------------------------------------------------------------
extern "C" void kernel_launch(void* const* d_in, const int* in_sizes, int n_in,
                              void* d_out, int out_size, void* d_ws, size_t ws_size,
                              hipStream_t stream)
{
    const float* x      = (const float*)d_in[0];
    const int*   neigh  = (const int*)  d_in[1];
    const float* w_sage = (const float*)d_in[2];
    const float* b_sage = (const float*)d_in[3];
    const float* lin1_w = (const float*)d_in[4];
    const float* lin1_b = (const float*)d_in[5];
    const float* bn_g   = (const float*)d_in[6];
    const float* bn_b   = (const float*)d_in[7];
    const float* lin2_w = (const float*)d_in[8];
    const float* lin2_b = (const float*)d_in[9];
    float* out = (float*)d_out;

    // ws layout (floats): v1part 32768 | v2part 32768 | z 8192
    float* v1part = (float*)d_ws;
    float* v2part = v1part + 32768;
    float* z      = v2part + 32768;

    stream_agg <<<2 * BDIM, 256, 0, stream>>>(x, neigh, v1part, v2part);
    mlp_z      <<<BDIM, 256, 0, stream>>>(x, v1part, v2part, w_sage, b_sage,
                                          lin1_w, lin1_b, z);
    head_kernel<<<1, 128, 0, stream>>>(z, bn_g, bn_b, lin2_w, lin2_b, out);
}

// Round 8
// 129.826 us; speedup vs baseline: 1.0311x; 1.0005x over previous
//
#include <hip/hip_runtime.h>
#include <hip/hip_bf16.h>
#include <math.h>

// Problem constants
#define BDIM    128   // batch graphs
#define N_NODES 512
#define KNB     10
#define FDIM    128
#define CDIM    40

// ---------------------------------------------------------------------------
// ALGEBRA (verified on-HW R2-R7, absmax 0.0): both SAGE layers are affine and
// only h[:,0,:] is consumed. With A_l/B_l = mp/self halves of w_sage[l]:
//   v1[b] = sum_{k,j} x[b, neigh[b, nb_k, j]]   (nb_k = neigh[b,0,k])
//   v2[b] = sum_k x[b, nb_k]
//   v4[b] = x[b,0]
//   p = A1·(0.01v1) + B1·(0.1v2) + b0
//   q = A1·(0.1v2)  + B1·v4      + b0
//   r = A2·p + B2·q + b1
//   z = L1·r + lin1_b
// then BatchNorm(batch)+ReLU+lin2+softmax.
//
// R8: EXACT reproduction of R3 (best measurement, 126.9 us). R3-R7 span
// 126.9-141.4 with three structurally different designs (gather / register-
// prefetch / bandwidth-streaming) landing within +-4 us of 130 despite ~3x
// differences in theoretical kernel time -- evidence that the measurement is
// dominated by the harness's per-iteration reset (268 MB poison fill at
// ~43 us + input restore) plus a design-invariant cold-page cost on x
// (every variant touches all of x's pages cold each replay). This round is
// the controlled reproducibility test of the best-known artifact.
// ---------------------------------------------------------------------------

__global__ __launch_bounds__(256) void fused_z(
    const float* __restrict__ x,       // (128,512,128)
    const int*   __restrict__ neigh,   // (128,512,10)
    const float* __restrict__ w_sage,  // (2,128,256)
    const float* __restrict__ b_sage,  // (2,128)
    const float* __restrict__ lin1_w,  // (64,128)
    const float* __restrict__ lin1_b,  // (64)
    float*       __restrict__ z)       // (128,64)
{
    __shared__ int   nb0s[16];
    __shared__ int   l2s[112];
    __shared__ float part[2][2][128];   // reused scratch across stages
    __shared__ float vs0[128], vs1[128], vs2[128];
    __shared__ float pv[128], qv[128], rv[128];
    __shared__ float zpart[4][64];

    const int b   = blockIdx.x;
    const int tid = threadIdx.x;
    const int* nbB = neigh + b * (N_NODES * KNB);

    // ---- stage 0: 2-hop index lists ----
    if (tid < 10) nb0s[tid] = nbB[tid];                 // neigh[b,0,:]
    __syncthreads();
    if (tid < 100) {
        int k = tid / 10, jj = tid - k * 10;
        l2s[tid] = nbB[nb0s[k] * KNB + jj];             // neigh[b, nb_k, jj]
    }
    __syncthreads();

    // ---- stage 1: gather-sum v1, v2, v4 ----
    const int f = tid & 127;
    const int h = tid >> 7;
    const float* xb = x + (size_t)b * (N_NODES * FDIM);
    {
        float s1 = 0.f, s2 = 0.f;
        #pragma unroll 10
        for (int t = h * 50; t < h * 50 + 50; ++t) s1 += xb[l2s[t] * FDIM + f];
        #pragma unroll
        for (int k = h * 5; k < h * 5 + 5; ++k)    s2 += xb[nb0s[k] * FDIM + f];
        part[0][h][f] = s1;
        part[1][h][f] = s2;
    }
    __syncthreads();
    if (h == 0) {
        vs0[f] = (part[0][0][f] + part[0][1][f]) * 0.01f;   // 0.01*v1
        vs1[f] = (part[1][0][f] + part[1][1][f]) * 0.1f;    // 0.1*v2
        vs2[f] = xb[f];                                     // v4
    }
    __syncthreads();

    // ---- stage 2: p = A1*vs0 + B1*vs1, q = A1*vs1 + B1*vs2 ----
    // thread (g, half): row g of w_sage layer 0, f-range [half*64, half*64+64)
    {
        const int g = tid & 127, half = tid >> 7;
        const float4* w4 = (const float4*)(w_sage + g * 256);
        float p0 = 0.f, p1 = 0.f, q0 = 0.f, q1 = 0.f;
        #pragma unroll
        for (int i = 0; i < 16; ++i) {
            int f4 = half * 16 + i;          // A1 segment
            float4 w = w4[f4];
            int fb = f4 * 4;
            p0 = fmaf(w.x, vs0[fb + 0], p0); p1 = fmaf(w.y, vs0[fb + 1], p1);
            p0 = fmaf(w.z, vs0[fb + 2], p0); p1 = fmaf(w.w, vs0[fb + 3], p1);
            q0 = fmaf(w.x, vs1[fb + 0], q0); q1 = fmaf(w.y, vs1[fb + 1], q1);
            q0 = fmaf(w.z, vs1[fb + 2], q0); q1 = fmaf(w.w, vs1[fb + 3], q1);
        }
        #pragma unroll
        for (int i = 0; i < 16; ++i) {
            int f4 = 32 + half * 16 + i;     // B1 segment
            float4 w = w4[f4];
            int fb = (f4 - 32) * 4;
            p0 = fmaf(w.x, vs1[fb + 0], p0); p1 = fmaf(w.y, vs1[fb + 1], p1);
            p0 = fmaf(w.z, vs1[fb + 2], p0); p1 = fmaf(w.w, vs1[fb + 3], p1);
            q0 = fmaf(w.x, vs2[fb + 0], q0); q1 = fmaf(w.y, vs2[fb + 1], q1);
            q0 = fmaf(w.z, vs2[fb + 2], q0); q1 = fmaf(w.w, vs2[fb + 3], q1);
        }
        part[0][half][g] = p0 + p1;
        part[1][half][g] = q0 + q1;
    }
    __syncthreads();
    if (h == 0) {
        float b0 = b_sage[f];
        pv[f] = part[0][0][f] + part[0][1][f] + b0;
        qv[f] = part[1][0][f] + part[1][1][f] + b0;
    }
    __syncthreads();

    // ---- stage 3: r = A2*p + B2*q + b1 ----
    {
        const int g2 = tid & 127, half = tid >> 7;
        const float4* w4 = (const float4*)(w_sage + 32768 + g2 * 256 + half * 128);
        const float* vv = half ? qv : pv;
        float a0 = 0.f, a1 = 0.f;
        #pragma unroll
        for (int i = 0; i < 32; ++i) {
            float4 w = w4[i];
            int gb = i * 4;
            a0 = fmaf(w.x, vv[gb + 0], a0); a1 = fmaf(w.y, vv[gb + 1], a1);
            a0 = fmaf(w.z, vv[gb + 2], a0); a1 = fmaf(w.w, vv[gb + 3], a1);
        }
        part[0][half][g2] = a0 + a1;
    }
    __syncthreads();
    if (h == 0) rv[f] = b_sage[128 + f] + part[0][0][f] + part[0][1][f];
    __syncthreads();

    // ---- stage 4: z = L1*r + lin1_b ----
    {
        const int j = tid & 63, qt = tid >> 6;
        const float4* w4 = (const float4*)(lin1_w + j * 128 + qt * 32);
        float a0 = 0.f, a1 = 0.f;
        #pragma unroll
        for (int i = 0; i < 8; ++i) {
            float4 w = w4[i];
            int gb = qt * 32 + i * 4;
            a0 = fmaf(w.x, rv[gb + 0], a0); a1 = fmaf(w.y, rv[gb + 1], a1);
            a0 = fmaf(w.z, rv[gb + 2], a0); a1 = fmaf(w.w, rv[gb + 3], a1);
        }
        zpart[qt][j] = a0 + a1;
    }
    __syncthreads();
    if (tid < 64)
        z[b * 64 + tid] = lin1_b[tid] + zpart[0][tid] + zpart[1][tid]
                        + zpart[2][tid] + zpart[3][tid];
}

// ---------------------------------------------------------------------------
// BatchNorm (over batch) + ReLU + lin2 + softmax. Single block. (verified R1)
// ---------------------------------------------------------------------------
__global__ __launch_bounds__(128) void head_kernel(
    const float* __restrict__ z,      // (128, 64)
    const float* __restrict__ gamma,  // (64)
    const float* __restrict__ beta,   // (64)
    const float* __restrict__ w2,     // (40, 64)
    const float* __restrict__ b2,     // (40)
    float*       __restrict__ out)    // (128, 40)
{
    __shared__ float zs[128][65];
    __shared__ float sc[64], sh[64];
    const int tid = threadIdx.x;

    for (int i = 0; i < 64; ++i) {
        int idx = i * 128 + tid;
        zs[idx >> 6][idx & 63] = z[idx];
    }
    __syncthreads();

    if (tid < 64) {
        float s = 0.f, ss = 0.f;
        for (int i = 0; i < 128; ++i) {
            float v = zs[i][tid];
            s += v; ss += v * v;
        }
        float mu  = s * (1.f / 128.f);
        float var = ss * (1.f / 128.f) - mu * mu;
        float rs  = rsqrtf(var + 1e-5f) * gamma[tid];
        sc[tid] = rs;
        sh[tid] = beta[tid] - mu * rs;
    }
    __syncthreads();

    {
        int j = tid & 63;
        for (int i = tid >> 6; i < 128; i += 2) {
            float v = fmaf(zs[i][j], sc[j], sh[j]);
            zs[i][j] = fmaxf(v, 0.f);
        }
    }
    __syncthreads();

    {
        int i = tid;
        float lg[CDIM];
        float mx = -1e30f;
        #pragma unroll 4
        for (int c = 0; c < CDIM; ++c) {
            const float* w = w2 + c * 64;
            float s = b2[c];
            for (int ff = 0; ff < 64; ++ff) s = fmaf(zs[i][ff], w[ff], s);
            lg[c] = s;
            mx = fmaxf(mx, s);
        }
        float den = 0.f;
        for (int c = 0; c < CDIM; ++c) {
            lg[c] = __expf(lg[c] - mx);
            den += lg[c];
        }
        float inv = 1.f / den;
        for (int c = 0; c < CDIM; ++c) out[i * CDIM + c] = lg[c] * inv;
    }
}

// ---------------------------------------------------------------------------
extern "C" void kernel_launch(void* const* d_in, const int* in_sizes, int n_in,
                              void* d_out, int out_size, void* d_ws, size_t ws_size,
                              hipStream_t stream)
{
    const float* x      = (const float*)d_in[0];
    const int*   neigh  = (const int*)  d_in[1];
    const float* w_sage = (const float*)d_in[2];
    const float* b_sage = (const float*)d_in[3];
    const float* lin1_w = (const float*)d_in[4];
    const float* lin1_b = (const float*)d_in[5];
    const float* bn_g   = (const float*)d_in[6];
    const float* bn_b   = (const float*)d_in[7];
    const float* lin2_w = (const float*)d_in[8];
    const float* lin2_b = (const float*)d_in[9];
    float* out = (float*)d_out;

    float* z = (float*)d_ws;   // 128*64 floats

    fused_z    <<<BDIM, 256, 0, stream>>>(x, neigh, w_sage, b_sage,
                                          lin1_w, lin1_b, z);
    head_kernel<<<1, 128, 0, stream>>>(z, bn_g, bn_b, lin2_w, lin2_b, out);
}